// Round 10
// baseline (1063.869 us; speedup 1.0000x reference)
//
#include <hip/hip_runtime.h>

// LSTM decoder B=2048, Z=64, A=8, H=512, T=64.
// Round 10: persistent cooperative kernel, fence-free flag sync.
// 512 WGs x 256 thr (2 WG/CU). Cluster = 16 nt-WGs sharing a 64-row batch
// tile; h exchanged via relaxed agent-scope atomics (device-coherent path,
// no L1/L2 flushes). W streamed from L2 via global_load_lds + XOR swizzle,
// counted vmcnt. c, bias in registers across all 64 steps. Fused projection.
// Fallback: round-9 multi-launch path (passed @926us) if coop launch fails.

#define HID   512
#define TSTEP 64
#define KCAT  576

typedef unsigned long long u64;
typedef __attribute__((ext_vector_type(8))) short bf16x8;
typedef __attribute__((ext_vector_type(4))) float f32x4;

__device__ inline unsigned short f2bf(float f) {
  unsigned int u = __builtin_bit_cast(unsigned int, f);
  unsigned int r = (u + 0x7fffu + ((u >> 16) & 1u)) >> 16;
  return (unsigned short)r;
}
__device__ inline float sigm(float x) { return 1.0f / (1.0f + __expf(-x)); }
__device__ inline float tanh_f(float x) { return 1.0f - 2.0f / (__expf(2.0f * x) + 1.0f); }

__device__ inline void gl16(const unsigned short* g, unsigned short* l) {
  __builtin_amdgcn_global_load_lds(
      (const __attribute__((address_space(1))) unsigned int*)g,
      (__attribute__((address_space(3))) unsigned int*)l, 16, 0, 0);
}

// ---- merged prep: wcat (bf16 [W_hh|W_ih_z]), zbf, bias ----
__global__ void k_prep(const float* __restrict__ z, const float* __restrict__ wih,
                       const float* __restrict__ whh, const float* __restrict__ bih,
                       const float* __restrict__ bhh,
                       unsigned short* __restrict__ wcat, unsigned short* __restrict__ zbf,
                       float* __restrict__ bias) {
  int c = blockIdx.x * 256 + threadIdx.x;
  if (c < 147456) {
    int n = c / 72, kc = (c % 72) * 8;
    unsigned short u[8];
#pragma unroll
    for (int e = 0; e < 8; ++e) {
      int k = kc + e;
      float v = (k < 512) ? whh[(size_t)n * 512 + k] : wih[(size_t)n * 72 + 8 + (k - 512)];
      u[e] = f2bf(v);
    }
    *(bf16x8*)&wcat[(size_t)n * KCAT + kc] = *(bf16x8*)u;
  } else if (c < 163840) {
    int i = c - 147456;
    int row = i >> 3, kc = (i & 7) * 8;
    unsigned short u[8];
#pragma unroll
    for (int e = 0; e < 8; ++e) u[e] = f2bf(z[(size_t)row * 64 + kc + e]);
    *(bf16x8*)&zbf[(size_t)row * 64 + kc] = *(bf16x8*)u;
  } else if (c < 165888) {
    int n = c - 163840;
    bias[n] = bih[n] + bhh[n];
  }
}

__global__ void k_zero(int* __restrict__ flags) {
  int g = blockIdx.x * 256 + threadIdx.x;
  if (g < TSTEP * 32) flags[g] = 0;
}

struct P {
  const unsigned short *wcat, *zbf;
  const float *bias, *wout, *bout;
  unsigned short *h0, *h1;
  float* out;
  int* flags;
};

#define ATOMLD(PTR) __hip_atomic_load((PTR), __ATOMIC_RELAXED, __HIP_MEMORY_SCOPE_AGENT)
#define ATOMST(PTR, V) __hip_atomic_store((PTR), (V), __ATOMIC_RELAXED, __HIP_MEMORY_SCOPE_AGENT)

// LDS layout (bytes): Bb0 0 | Bb1 16384 | Ab0 32768 | Ab1 40960 | zA 49152
//                     wo 57344 | hO 73728 ; total 78848
#define SMEM_SZ 78848

__global__ __launch_bounds__(256, 2) void k_persist(P p) {
  extern __shared__ char smem[];
  unsigned short* Bb[2] = {(unsigned short*)smem, (unsigned short*)(smem + 16384)};
  unsigned short* Ab[2] = {(unsigned short*)(smem + 32768), (unsigned short*)(smem + 40960)};
  unsigned short* zA    = (unsigned short*)(smem + 49152);
  unsigned short* wo    = (unsigned short*)(smem + 57344);
  unsigned short* hO    = (unsigned short*)(smem + 73728);

  const int bid = blockIdx.x;
  const int nt = bid >> 5, bt = bid & 31;     // bid%8 == bt%8 (XCD locality hint)
  const int tid = threadIdx.x;
  const int lane = tid & 63;
  const int wv = tid >> 6;
  const int mq = wv >> 1, nh = wv & 1;
  const int cl = lane & 15, q8 = lane >> 4;
  const int b0 = bt * 64, j0 = nt * 32;

  // ---- B staging (r9-verified): XOR-swizzled source, wave-linear LDS dest ----
  const int rS = tid >> 3;
  const int xS = ((tid & 7) ^ (rS & 7)) * 8;
  const unsigned short* srcB[4];
#pragma unroll
  for (int k = 0; k < 4; ++k) {
    int rB = k * 32 + rS;
    int n = (rB >> 5) * HID + j0 + (rB & 31);
    srcB[k] = p.wcat + (size_t)n * KCAT + xS;
  }
#define STAGEB(BUF, CHUNK) { _Pragma("unroll") for (int k4 = 0; k4 < 4; ++k4) \
    gl16(srcB[k4] + (CHUNK) * 64, &Bb[BUF][(k4 * 256 + wv * 64) * 8]); }

  // ---- A mapping: thread owns 32B of each chunk (row arow, 16-short seg aseg) ----
  const int arow = tid >> 2, aseg = tid & 3;
  const int aoff0 = arow * 64 + (((aseg * 2 + 0) ^ (arow & 7)) * 8);
  const int aoff1 = arow * 64 + (((aseg * 2 + 1) ^ (arow & 7)) * 8);
#define AWRITE(DST, R) do { \
    *(u64*)&(DST)[aoff0] = (R)[0]; *(u64*)&(DST)[aoff0 + 4] = (R)[1]; \
    *(u64*)&(DST)[aoff1] = (R)[2]; *(u64*)&(DST)[aoff1 + 4] = (R)[3]; } while (0)

  // ---- one-time LDS init: z tile (swizzled), W_out (nt==0 only) ----
  {
    const u64* zp = (const u64*)(p.zbf + (size_t)(b0 + arow) * 64) + aseg * 4;
    u64 zr[4] = {zp[0], zp[1], zp[2], zp[3]};
    AWRITE(zA, zr);
  }
  if (nt == 0) {
    int r = tid >> 4, s0 = tid & 15;
#pragma unroll
    for (int i = 0; i < 4; ++i) {
      int s = s0 + i * 16;
      unsigned short u[8] = {0, 0, 0, 0, 0, 0, 0, 0};
      if (r < 8) {
        const float* wp = p.wout + (size_t)r * 512 + s * 8;
        float4 f0 = *(const float4*)wp;
        float4 f1 = *(const float4*)(wp + 4);
        u[0] = f2bf(f0.x); u[1] = f2bf(f0.y); u[2] = f2bf(f0.z); u[3] = f2bf(f0.w);
        u[4] = f2bf(f1.x); u[5] = f2bf(f1.y); u[6] = f2bf(f1.z); u[7] = f2bf(f1.w);
      }
      int off = r * 512 + (s >> 3) * 64 + (((s & 7) ^ (r & 7)) * 8);
      *(bf16x8*)&wo[off] = *(bf16x8*)u;
    }
  }

  // ---- persistent registers ----
  float bias_r[4];
#pragma unroll
  for (int g = 0; g < 4; ++g) bias_r[g] = p.bias[g * HID + j0 + nh * 16 + cl];
  f32x4 c0 = {0, 0, 0, 0}, c1 = {0, 0, 0, 0};
  f32x4 acc[4][2];
  f32x4 accp0, accp1;
  const float boutv = (cl < 8) ? p.bout[cl] : 0.0f;

  auto mfma_block = [&](const unsigned short* Al, const unsigned short* Bl,
                        int kkv, bool doProj) {
#pragma unroll
    for (int ks = 0; ks < 2; ++ks) {
      const int sx = ((ks * 4 + q8) ^ (cl & 7)) * 8;
      bf16x8 af0 = *(const bf16x8*)&Al[(mq * 32 + cl) * 64 + sx];
      bf16x8 af1 = *(const bf16x8*)&Al[(mq * 32 + 16 + cl) * 64 + sx];
#pragma unroll
      for (int g = 0; g < 4; ++g) {
        bf16x8 bf = *(const bf16x8*)&Bl[(g * 32 + nh * 16 + cl) * 64 + sx];
        acc[g][0] = __builtin_amdgcn_mfma_f32_16x16x32_bf16(af0, bf, acc[g][0], 0, 0, 0);
        acc[g][1] = __builtin_amdgcn_mfma_f32_16x16x32_bf16(af1, bf, acc[g][1], 0, 0, 0);
      }
      if (doProj && nh == 0 && kkv < 8) {
        bf16x8 wf = *(const bf16x8*)&wo[cl * 512 + kkv * 64 + sx];
        accp0 = __builtin_amdgcn_mfma_f32_16x16x32_bf16(af0, wf, accp0, 0, 0, 0);
        accp1 = __builtin_amdgcn_mfma_f32_16x16x32_bf16(af1, wf, accp1, 0, 0, 0);
      }
    }
  };

  auto cell_and_store = [&](unsigned short* hcur, int t) {
#pragma unroll
    for (int fm = 0; fm < 2; ++fm) {
      f32x4 cold = fm ? c1 : c0;
      f32x4 cn;
#pragma unroll
      for (int r = 0; r < 4; ++r) {
        float iv = sigm(acc[0][fm][r]);
        float fv = sigm(acc[1][fm][r]);
        float gv = tanh_f(acc[2][fm][r]);
        float ov = sigm(acc[3][fm][r]);
        float cv = fv * cold[r] + iv * gv;
        cn[r] = cv;
        hO[(mq * 32 + fm * 16 + q8 * 4 + r) * 40 + nh * 16 + cl] = f2bf(ov * tanh_f(cv));
      }
      if (fm) c1 = cn; else c0 = cn;
    }
    __syncthreads();   // hO ready
    u64 u0 = *(const u64*)&hO[arow * 40 + aseg * 8];
    u64 u1 = *(const u64*)&hO[arow * 40 + aseg * 8 + 4];
    u64* dst = (u64*)(hcur + (size_t)(b0 + arow) * HID + j0 + aseg * 8);
    ATOMST(dst, u0);
    ATOMST(dst + 1, u1);
    // release: own stores complete, then all threads, then count
    asm volatile("s_waitcnt vmcnt(0)" ::: "memory");
    __syncthreads();
    if (tid == 0)
      __hip_atomic_fetch_add(&p.flags[t * 32 + bt], 1, __ATOMIC_RELAXED,
                             __HIP_MEMORY_SCOPE_AGENT);
  };

#define SPIN(IDX) do { if (tid == 0) { \
      while (__hip_atomic_load(&p.flags[IDX], __ATOMIC_RELAXED, \
                               __HIP_MEMORY_SCOPE_AGENT) < 16) \
        __builtin_amdgcn_s_sleep(2); } __syncthreads(); } while (0)
#define MEMBAR() asm volatile("" ::: "memory")
#define HWBAR()  __builtin_amdgcn_s_barrier()

  // ================= t = 0 : z-chunk only =================
  STAGEB(0, 8);
  asm volatile("s_waitcnt vmcnt(0) lgkmcnt(0)" ::: "memory");
  HWBAR(); MEMBAR();
#pragma unroll
  for (int g = 0; g < 4; ++g) {
    f32x4 v = {bias_r[g], bias_r[g], bias_r[g], bias_r[g]};
    acc[g][0] = v; acc[g][1] = v;
  }
  mfma_block(zA, Bb[0], 8, false);
  MEMBAR(); HWBAR(); MEMBAR();
  cell_and_store(p.h0, 0);

  // ================= t = 1 .. 63 =================
  for (int t = 1; t < TSTEP; ++t) {
    const unsigned short* hprev = (t & 1) ? p.h0 : p.h1;
    unsigned short* hcur = (t & 1) ? p.h1 : p.h0;
    SPIN((t - 1) * 32 + bt);

    const u64* hrow = (const u64*)(hprev + (size_t)(b0 + arow) * HID);
    u64 ra[2][4];
#pragma unroll
    for (int i = 0; i < 4; ++i) ra[0][i] = ATOMLD(hrow + 0 * 16 + aseg * 4 + i);
    STAGEB(0, 0);
#pragma unroll
    for (int i = 0; i < 4; ++i) ra[1][i] = ATOMLD(hrow + 1 * 16 + aseg * 4 + i);
    STAGEB(1, 1);
    AWRITE(Ab[0], ra[0]);
    asm volatile("s_waitcnt vmcnt(8) lgkmcnt(0)" ::: "memory");
    HWBAR(); MEMBAR();

#pragma unroll
    for (int g = 0; g < 4; ++g) {
      f32x4 v = {bias_r[g], bias_r[g], bias_r[g], bias_r[g]};
      acc[g][0] = v; acc[g][1] = v;
    }
    {
      f32x4 v = {boutv, boutv, boutv, boutv};
      accp0 = v; accp1 = v;
    }

#pragma unroll
    for (int kk = 0; kk <= 8; ++kk) {
      mfma_block(kk < 8 ? Ab[kk & 1] : zA, Bb[kk & 1], kk, (nt == 0));
      if (kk == 8) break;
      MEMBAR(); HWBAR(); MEMBAR();
      if (kk + 2 <= 7) {
        AWRITE(Ab[(kk + 1) & 1], ra[(kk + 1) & 1]);
#pragma unroll
        for (int i = 0; i < 4; ++i)
          ra[kk & 1][i] = ATOMLD(hrow + (kk + 2) * 16 + aseg * 4 + i);
        STAGEB(kk & 1, kk + 2);
        asm volatile("s_waitcnt vmcnt(8) lgkmcnt(0)" ::: "memory");
      } else if (kk + 2 == 8) {
        AWRITE(Ab[(kk + 1) & 1], ra[(kk + 1) & 1]);
        STAGEB(kk & 1, 8);
        asm volatile("s_waitcnt vmcnt(4) lgkmcnt(0)" ::: "memory");
      } else {
        asm volatile("s_waitcnt vmcnt(0) lgkmcnt(0)" ::: "memory");
      }
      MEMBAR(); HWBAR(); MEMBAR();
    }

    if (nt == 0 && nh == 0 && cl < 8) {
      const int tt = t - 1;
#pragma unroll
      for (int r = 0; r < 4; ++r) {
        int b = b0 + mq * 32 + q8 * 4 + r;
        p.out[((size_t)b * 64 + tt) * 8 + cl] = accp0[r];
        p.out[((size_t)(b + 16) * 64 + tt) * 8 + cl] = accp1[r];
      }
    }
    cell_and_store(hcur, t);
  }

  // ================= epilogue: proj of h(63) (nt==0 WGs only) =================
  if (nt == 0) {
    SPIN(63 * 32 + bt);
    const u64* hrow = (const u64*)(p.h1 + (size_t)(b0 + arow) * HID);  // t=63 wrote h1
    u64 rr[32];
#pragma unroll
    for (int kk = 0; kk < 8; ++kk)
#pragma unroll
      for (int i = 0; i < 4; ++i)
        rr[kk * 4 + i] = ATOMLD(hrow + kk * 16 + aseg * 4 + i);
    f32x4 ap0 = {boutv, boutv, boutv, boutv};
    f32x4 ap1 = ap0;
#pragma unroll
    for (int kk = 0; kk < 8; ++kk) {
      AWRITE(Ab[0], (&rr[kk * 4]));
      asm volatile("s_waitcnt lgkmcnt(0)" ::: "memory");
      HWBAR(); MEMBAR();
#pragma unroll
      for (int ks = 0; ks < 2; ++ks) {
        const int sx = ((ks * 4 + q8) ^ (cl & 7)) * 8;
        bf16x8 af0 = *(const bf16x8*)&Ab[0][(mq * 32 + cl) * 64 + sx];
        bf16x8 af1 = *(const bf16x8*)&Ab[0][(mq * 32 + 16 + cl) * 64 + sx];
        if (nh == 0) {
          bf16x8 wf = *(const bf16x8*)&wo[cl * 512 + kk * 64 + sx];
          ap0 = __builtin_amdgcn_mfma_f32_16x16x32_bf16(af0, wf, ap0, 0, 0, 0);
          ap1 = __builtin_amdgcn_mfma_f32_16x16x32_bf16(af1, wf, ap1, 0, 0, 0);
        }
      }
      MEMBAR(); HWBAR(); MEMBAR();
    }
    if (nh == 0 && cl < 8) {
#pragma unroll
      for (int r = 0; r < 4; ++r) {
        int b = b0 + mq * 32 + q8 * 4 + r;
        p.out[((size_t)b * 64 + 63) * 8 + cl] = ap0[r];
        p.out[((size_t)(b + 16) * 64 + 63) * 8 + cl] = ap1[r];
      }
    }
  }
#undef STAGEB
#undef AWRITE
#undef SPIN
#undef MEMBAR
#undef HWBAR
}

// ================= fallback: round-9 multi-launch path (passed @926us) =================
template <int GATES, int PROJ>
__global__ __launch_bounds__(256, 2) void k_stepF(
    const unsigned short* __restrict__ hprev, unsigned short* __restrict__ hnext,
    const unsigned short* __restrict__ wcat, const unsigned short* __restrict__ zbf,
    const float* __restrict__ wout, const float* __restrict__ bias,
    const float* __restrict__ bout, float* __restrict__ cst,
    float* __restrict__ out, int t) {
  __shared__ unsigned short Ab[2][64 * 64];
  __shared__ unsigned short Bb[2][128 * 64];
  __shared__ unsigned short wo_lds[16 * 512];
  __shared__ unsigned short hO[64 * 40];

  const int bid = blockIdx.x;
  const int nt = GATES ? (((bid & 7) << 1) | ((bid >> 8) & 1)) : 0;
  const int bt = GATES ? ((bid >> 3) & 31) : bid;
  const int tid = threadIdx.x;
  const int lane = tid & 63;
  const int wv = tid >> 6;
  const int mq = wv >> 1, nh = wv & 1;
  const int cl = lane & 15, q8 = lane >> 4;
  const int b0 = bt * 64, j0 = nt * 32;

  const int rA = tid >> 3;
  const int xA = ((tid & 7) ^ (rA & 7)) * 8;
  const unsigned short* srcA0 = hprev + (size_t)(b0 + rA) * HID + xA;
  const unsigned short* srcA1 = hprev + (size_t)(b0 + 32 + rA) * HID + xA;
  const unsigned short* srcZ0 = zbf + (size_t)(b0 + rA) * 64 + xA;
  const unsigned short* srcZ1 = zbf + (size_t)(b0 + 32 + rA) * 64 + xA;
  const unsigned short* srcB[4];
#pragma unroll
  for (int k = 0; k < 4; ++k) {
    int rB = k * 32 + rA;
    int n = (rB >> 5) * HID + j0 + (rB & 31);
    srcB[k] = wcat + (size_t)n * KCAT + xA;
  }

  auto do_stage = [&](int buf, int kkv) {
    if (GATES) {
      if (kkv == 8) {
        gl16(srcZ0, &Ab[buf][(wv * 64) * 8]);
        gl16(srcZ1, &Ab[buf][(256 + wv * 64) * 8]);
      } else {
        gl16(srcA0 + kkv * 64, &Ab[buf][(wv * 64) * 8]);
        gl16(srcA1 + kkv * 64, &Ab[buf][(256 + wv * 64) * 8]);
      }
#pragma unroll
      for (int k = 0; k < 4; ++k)
        gl16(srcB[k] + kkv * 64, &Bb[buf][(k * 256 + wv * 64) * 8]);
    } else {
      gl16(srcA0 + kkv * 64, &Ab[buf][(wv * 64) * 8]);
      gl16(srcA1 + kkv * 64, &Ab[buf][(256 + wv * 64) * 8]);
    }
  };

  if (PROJ) {
    int r = tid >> 4, s0 = tid & 15;
#pragma unroll
    for (int i = 0; i < 4; ++i) {
      int s = s0 + i * 16;
      unsigned short u[8] = {0, 0, 0, 0, 0, 0, 0, 0};
      if (r < 8) {
        const float* wp = wout + (size_t)r * 512 + s * 8;
        float4 f0 = *(const float4*)wp;
        float4 f1 = *(const float4*)(wp + 4);
        u[0] = f2bf(f0.x); u[1] = f2bf(f0.y); u[2] = f2bf(f0.z); u[3] = f2bf(f0.w);
        u[4] = f2bf(f1.x); u[5] = f2bf(f1.y); u[6] = f2bf(f1.z); u[7] = f2bf(f1.w);
      }
      int off = r * 512 + (s >> 3) * 64 + (((s & 7) ^ (r & 7)) * 8);
      *(bf16x8*)&wo_lds[off] = *(bf16x8*)u;
    }
  }

  f32x4 acc[4][2];
  if (GATES) {
#pragma unroll
    for (int g = 0; g < 4; ++g) {
      float bv = bias[g * HID + j0 + nh * 16 + cl];
      f32x4 v = {bv, bv, bv, bv};
      acc[g][0] = v; acc[g][1] = v;
    }
  }
  f32x4 accp0 = {0, 0, 0, 0}, accp1 = {0, 0, 0, 0};
  if (PROJ) {
    float bo = (cl < 8) ? bout[cl] : 0.0f;
    f32x4 v = {bo, bo, bo, bo};
    accp0 = v; accp1 = v;
  }

  const size_t cbase = ((size_t)bid * 256 + tid) * 8;
  f32x4 c0 = {0, 0, 0, 0}, c1 = {0, 0, 0, 0};
  if (GATES && t > 0) { c0 = *(const f32x4*)&cst[cbase]; c1 = *(const f32x4*)&cst[cbase + 4]; }

  auto mfma_block = [&](int bu, int kkv) {
    const unsigned short* Al = Ab[bu];
    const unsigned short* Bl = Bb[bu];
#pragma unroll
    for (int ks = 0; ks < 2; ++ks) {
      const int sx = ((ks * 4 + q8) ^ (cl & 7)) * 8;
      bf16x8 af0 = *(const bf16x8*)&Al[(mq * 32 + cl) * 64 + sx];
      bf16x8 af1 = *(const bf16x8*)&Al[(mq * 32 + 16 + cl) * 64 + sx];
      if (GATES) {
#pragma unroll
        for (int g = 0; g < 4; ++g) {
          bf16x8 bf = *(const bf16x8*)&Bl[(g * 32 + nh * 16 + cl) * 64 + sx];
          acc[g][0] = __builtin_amdgcn_mfma_f32_16x16x32_bf16(af0, bf, acc[g][0], 0, 0, 0);
          acc[g][1] = __builtin_amdgcn_mfma_f32_16x16x32_bf16(af1, bf, acc[g][1], 0, 0, 0);
        }
      }
      if (PROJ && nh == 0 && kkv < 8) {
        bf16x8 wf = *(const bf16x8*)&wo_lds[cl * 512 + kkv * 64 + sx];
        accp0 = __builtin_amdgcn_mfma_f32_16x16x32_bf16(af0, wf, accp0, 0, 0, 0);
        accp1 = __builtin_amdgcn_mfma_f32_16x16x32_bf16(af1, wf, accp1, 0, 0, 0);
      }
    }
  };

#define MEMBARF() asm volatile("" ::: "memory")
#define HWBARF()  __builtin_amdgcn_s_barrier()
  if (GATES && t == 0) {
    do_stage(0, 8);
    asm volatile("s_waitcnt vmcnt(0) lgkmcnt(0)" ::: "memory");
    HWBARF(); MEMBARF();
    mfma_block(0, 8);
  } else {
    do_stage(0, 0);
    do_stage(1, 1);
    if (GATES) asm volatile("s_waitcnt vmcnt(6) lgkmcnt(0)" ::: "memory");
    else       asm volatile("s_waitcnt vmcnt(2) lgkmcnt(0)" ::: "memory");
    HWBARF(); MEMBARF();
    const int kkEnd = GATES ? 8 : 7;
    for (int kk = 0;; ++kk) {
      mfma_block(kk & 1, kk);
      if (kk == kkEnd) break;
      MEMBARF(); HWBARF(); MEMBARF();
      if (kk + 2 <= kkEnd) {
        do_stage(kk & 1, kk + 2);
        if (GATES) asm volatile("s_waitcnt vmcnt(6)" ::: "memory");
        else       asm volatile("s_waitcnt vmcnt(2)" ::: "memory");
      } else {
        asm volatile("s_waitcnt vmcnt(0)" ::: "memory");
      }
      MEMBARF(); HWBARF(); MEMBARF();
    }
  }

  if (PROJ && nh == 0 && cl < 8) {
    const int tt = t - 1;
#pragma unroll
    for (int r = 0; r < 4; ++r) {
      int b = b0 + mq * 32 + q8 * 4 + r;
      out[((size_t)b * 64 + tt) * 8 + cl] = accp0[r];
      out[((size_t)(b + 16) * 64 + tt) * 8 + cl] = accp1[r];
    }
  }

  if (GATES) {
#pragma unroll
    for (int fm = 0; fm < 2; ++fm) {
      f32x4 cold = fm ? c1 : c0;
      f32x4 cn;
#pragma unroll
      for (int r = 0; r < 4; ++r) {
        float iv = sigm(acc[0][fm][r]);
        float fv = sigm(acc[1][fm][r]);
        float gv = tanh_f(acc[2][fm][r]);
        float ov = sigm(acc[3][fm][r]);
        float cv = fv * cold[r] + iv * gv;
        cn[r] = cv;
        hO[(mq * 32 + fm * 16 + q8 * 4 + r) * 40 + nh * 16 + cl] = f2bf(ov * tanh_f(cv));
      }
      if (fm) c1 = cn; else c0 = cn;
    }
    *(f32x4*)&cst[cbase] = c0;
    *(f32x4*)&cst[cbase + 4] = c1;
    __syncthreads();
    int row = tid >> 2, sg4 = tid & 3;
    unsigned short tmp[8];
#pragma unroll
    for (int e = 0; e < 8; ++e) tmp[e] = hO[row * 40 + sg4 * 8 + e];
    *(int4*)&hnext[(size_t)(b0 + row) * HID + j0 + sg4 * 8] = *(int4*)tmp;
  }
#undef MEMBARF
#undef HWBARF
}

extern "C" void kernel_launch(void* const* d_in, const int* in_sizes, int n_in,
                              void* d_out, int out_size, void* d_ws, size_t ws_size,
                              hipStream_t stream) {
  const float* z    = (const float*)d_in[0];
  const float* wih  = (const float*)d_in[1];
  const float* whh  = (const float*)d_in[2];
  const float* bih  = (const float*)d_in[3];
  const float* bhh  = (const float*)d_in[4];
  const float* wout = (const float*)d_in[5];
  const float* bout = (const float*)d_in[6];
  float* out = (float*)d_out;

  char* ws = (char*)d_ws;
  unsigned short* wcat = (unsigned short*)(ws);              // 2,359,296
  unsigned short* zbf  = (unsigned short*)(ws + 2359296);    //   262,144
  float* bias          = (float*)(ws + 2621440);             //     8,192
  unsigned short* h0   = (unsigned short*)(ws + 2629632);    // 2,097,152
  unsigned short* h1   = (unsigned short*)(ws + 4726784);    // 2,097,152
  int* flags           = (int*)(ws + 6823936);               //     8,192
  float* cst           = (float*)(ws + 6832128);             // 4,194,304 (fallback)

  k_prep<<<dim3(648), dim3(256), 0, stream>>>(z, wih, whh, bih, bhh, wcat, zbf, bias);
  k_zero<<<dim3(8), dim3(256), 0, stream>>>(flags);

  P pp;
  pp.wcat = wcat; pp.zbf = zbf; pp.bias = bias; pp.wout = wout; pp.bout = bout;
  pp.h0 = h0; pp.h1 = h1; pp.out = out; pp.flags = flags;

  hipFuncSetAttribute((const void*)k_persist,
                      hipFuncAttributeMaxDynamicSharedMemorySize, SMEM_SZ);
  void* args[] = {&pp};
  hipError_t e = hipLaunchCooperativeKernel((const void*)k_persist, dim3(512), dim3(256),
                                            args, SMEM_SZ, stream);
  if (e == hipSuccess) return;

  // ---- fallback: round-9 multi-launch ----
  for (int t = 0; t < TSTEP; ++t) {
    const unsigned short* hp = (t & 1) ? h0 : h1;
    unsigned short* hn = (t & 1) ? h1 : h0;
    if (t == 0)
      k_stepF<1, 0><<<dim3(512), dim3(256), 0, stream>>>(hp, hn, wcat, zbf, wout, bias,
                                                         bout, cst, out, t);
    else
      k_stepF<1, 1><<<dim3(512), dim3(256), 0, stream>>>(hp, hn, wcat, zbf, wout, bias,
                                                         bout, cst, out, t);
  }
  k_stepF<0, 1><<<dim3(32), dim3(256), 0, stream>>>(h1, h0, wcat, zbf, wout, bias,
                                                    bout, cst, out, TSTEP);
}